// Round 8
// baseline (168.442 us; speedup 1.0000x reference)
//
#include <hip/hip_runtime.h>

// PolyLinear: out[i] = b + sum_j W[j] * prod_k x_aug[i, idx[j,k]]
// Deterministic lex-order enumeration: deg1 W[0..31], deg2 W[32..559] (a<=b),
// deg3 W[560..6543] (a<=b<=c). Factorization per row:
//   acc = sum_a W1[a]*x_a
//       + sum_{a<=b} (x_a*x_b) * ( W2[a,b] + sum_{c>=b} W3[a,b,c]*x_c )
//
// V8 (resubmit — previous round's bench died to container infra, not the
// kernel). History: SMEM-weight path (V1/V7) is drain-bound: SMEM returns
// out-of-order -> every batch needs lgkmcnt(0) FULL drain -> no pipelining;
// V7 measured 44us @ VALUBusy 15% despite 4x ILP and spill-free regs.
// LDS-weight path pipelines (V4, R=2: ~12-18us, LDS-pipe-bound at
// 1768 b128/CU); R=4 halves LDS insts but V5/V6 spilled: the scheduler
// hoists MANY pairs' ds_read_b128 results (4 VGPR each) on top of x[128]
// -> transient pressure > any cap.
// V8 = V6 (LDS weights, R=4, 256-thr blocks, all 4 waves same part) +
// __builtin_amdgcn_sched_barrier(0) after each (a,b) pair: bounds in-flight
// LDS reads to <=8 b128 = 32 VGPRs -> demand ~175, no spill; within-pair
// ds_read/FMA interleave + 8 waves/CU TLP hide LDS latency.
// Budget: LDS pipe 8 waves x 94 b128 x 12cy ~ 3.8us/CU; VALU ~2.7us/SIMD.
// Cross-part reduce via atomicAdd on pre-zeroed out (proven 2MB, cheap).

#define NPART 16
#define TOTAL3 5984

__device__ __forceinline__ constexpr int off2(int a, int b) {
    // deg2 base 32; pairs (a<=b) lex order
    return 32 + 32 * a - (a * (a - 1)) / 2 + (b - a);
}

__device__ __forceinline__ constexpr int off3(int a, int b, int c) {
    // deg3 base 560; triples (a<=b<=c) lex order.
    // g3[a] = #triples with first index < a
    constexpr int g3[32] = {
        0,    528,  1024, 1489, 1924, 2330, 2708, 3059,
        3384, 3684, 3960, 4213, 4444, 4654, 4844, 5015,
        5168, 5304, 5424, 5529, 5620, 5698, 5764, 5819,
        5864, 5900, 5928, 5949, 5964, 5974, 5980, 5983};
    return 560 + g3[a] + 32 * (b - a) - ((b * (b - 1)) / 2 - (a * (a - 1)) / 2) + (c - b);
}

// #deg3 triples strictly before pair (a,b)'s c-run in lex order
__device__ __forceinline__ constexpr int cum3(int a, int b) {
    return off3(a, b, b) - 560;
}

// Balanced static ownership of pair (a,b): parts get ~equal deg3-FMA counts.
__device__ __forceinline__ constexpr int owner_of(int a, int b) {
    return (cum3(a, b) * NPART) / TOTAL3;  // monotone, 0..NPART-1
}

template <int PART>
__device__ __forceinline__ void eval_part4(const float* __restrict__ Wl,
                                           const float (&x0)[32],
                                           const float (&x1)[32],
                                           const float (&x2)[32],
                                           const float (&x3)[32],
                                           float& r0, float& r1,
                                           float& r2, float& r3) {
    float a0 = 0.0f, a1 = 0.0f, a2 = 0.0f, a3 = 0.0f;
#pragma unroll
    for (int a = 0; a < 32; ++a) {
#pragma unroll
        for (int b = a; b < 32; ++b) {
            if (owner_of(a, b) == PART) {  // compile-time filter
                if (a == b) {  // attach deg1 term for feature a here
                    const float w1 = Wl[a];
                    a0 = __builtin_fmaf(w1, x0[a], a0);
                    a1 = __builtin_fmaf(w1, x1[a], a1);
                    a2 = __builtin_fmaf(w1, x2[a], a2);
                    a3 = __builtin_fmaf(w1, x3[a], a3);
                }
                const float w2 = Wl[off2(a, b)];  // deg2 weight seeds chains
                float s0 = w2, s1 = w2, s2 = w2, s3 = w2;
#pragma unroll
                for (int c = b; c < 32; ++c) {
                    const float w = Wl[off3(a, b, c)];  // 1 LDS read, 4 FMAs
                    s0 = __builtin_fmaf(w, x0[c], s0);
                    s1 = __builtin_fmaf(w, x1[c], s1);
                    s2 = __builtin_fmaf(w, x2[c], s2);
                    s3 = __builtin_fmaf(w, x3[c], s3);
                }
                a0 = __builtin_fmaf(x0[a] * x0[b], s0, a0);
                a1 = __builtin_fmaf(x1[a] * x1[b], s1, a1);
                a2 = __builtin_fmaf(x2[a] * x2[b], s2, a2);
                a3 = __builtin_fmaf(x3[a] * x3[b], s3, a3);
                // Fence the scheduler at pair granularity: caps in-flight
                // ds_read_b128 (VGPR transients) that spilled V5/V6.
                __builtin_amdgcn_sched_barrier(0);
            }
        }
    }
    r0 = a0; r1 = a1; r2 = a2; r3 = a3;
}

// Block: 256 threads = 4 waves, ALL running the same part (bid & 15) on
// 1024 disjoint rows: thread t owns rows tile*1024 + r*256 + t, r=0..3.
// Cross-part reduce via atomicAdd (out pre-zeroed by hipMemsetAsync).
__global__ __launch_bounds__(256) void PolyLinear_40218073760341_kernel(
    const float* __restrict__ X,   // (rows, 32)
    const float* __restrict__ W,   // (6544,)
    const float* __restrict__ Bp,  // (1,)
    float* __restrict__ out)       // (rows,) — pre-zeroed
{
    const int part = blockIdx.x & (NPART - 1);
    const long rbase = (long)(blockIdx.x >> 4) * 1024 + threadIdx.x;

    __shared__ float Wl[6544];  // 26.2 KB staged weights

    // Stage W -> LDS (coalesced float4; 1636 vec4 over 256 threads)
    {
        const float4* Wg = (const float4*)W;
        float4* Wd = (float4*)Wl;
        for (int i = threadIdx.x; i < 1636; i += 256) Wd[i] = Wg[i];
    }

    // Load this thread's 4 rows into registers (float4 per row-chunk).
    float x0[32], x1[32], x2[32], x3[32];
    {
        const float4* p0 = (const float4*)(X + (rbase) * 32);
        const float4* p1 = (const float4*)(X + (rbase + 256) * 32);
        const float4* p2 = (const float4*)(X + (rbase + 512) * 32);
        const float4* p3 = (const float4*)(X + (rbase + 768) * 32);
#pragma unroll
        for (int i = 0; i < 8; ++i) {
            const float4 a = p0[i];
            x0[4 * i + 0] = a.x; x0[4 * i + 1] = a.y;
            x0[4 * i + 2] = a.z; x0[4 * i + 3] = a.w;
            const float4 b = p1[i];
            x1[4 * i + 0] = b.x; x1[4 * i + 1] = b.y;
            x1[4 * i + 2] = b.z; x1[4 * i + 3] = b.w;
            const float4 c = p2[i];
            x2[4 * i + 0] = c.x; x2[4 * i + 1] = c.y;
            x2[4 * i + 2] = c.z; x2[4 * i + 3] = c.w;
            const float4 d = p3[i];
            x3[4 * i + 0] = d.x; x3[4 * i + 1] = d.y;
            x3[4 * i + 2] = d.z; x3[4 * i + 3] = d.w;
        }
    }
    __syncthreads();  // Wl ready

    float r0 = 0.0f, r1 = 0.0f, r2 = 0.0f, r3 = 0.0f;
#define EVAL_CASE(P) \
    case P: eval_part4<P>(Wl, x0, x1, x2, x3, r0, r1, r2, r3); break;
    switch (part) {
        EVAL_CASE(0)  EVAL_CASE(1)  EVAL_CASE(2)  EVAL_CASE(3)
        EVAL_CASE(4)  EVAL_CASE(5)  EVAL_CASE(6)  EVAL_CASE(7)
        EVAL_CASE(8)  EVAL_CASE(9)  EVAL_CASE(10) EVAL_CASE(11)
        EVAL_CASE(12) EVAL_CASE(13) EVAL_CASE(14) EVAL_CASE(15)
    }
#undef EVAL_CASE

    // Bias added exactly once per row (by the part-0 block covering it).
    const float badd = (part == 0) ? Bp[0] : 0.0f;
    atomicAdd(&out[rbase], r0 + badd);
    atomicAdd(&out[rbase + 256], r1 + badd);
    atomicAdd(&out[rbase + 512], r2 + badd);
    atomicAdd(&out[rbase + 768], r3 + badd);
}

extern "C" void kernel_launch(void* const* d_in, const int* in_sizes, int n_in,
                              void* d_out, int out_size, void* d_ws, size_t ws_size,
                              hipStream_t stream) {
    const float* X  = (const float*)d_in[0];  // (32768, 32) fp32
    const float* W  = (const float*)d_in[1];  // (1, 6544) fp32
    const float* Bp = (const float*)d_in[2];  // (1,) fp32
    // d_in[3] = idx — deterministic, unused.
    float* out = (float*)d_out;

    const int rows = in_sizes[0] / 32;  // 32768
    hipMemsetAsync(out, 0, (size_t)rows * sizeof(float), stream);
    const int grid = (rows / 1024) * NPART;  // 32 tiles x 16 parts = 512
    PolyLinear_40218073760341_kernel<<<grid, 256, 0, stream>>>(X, W, Bp, out);
}

// Round 9
// 80.794 us; speedup vs baseline: 2.0848x; 2.0848x over previous
//
#include <hip/hip_runtime.h>

// PolyLinear: out[i] = b + sum_j W[j] * prod_k x_aug[i, idx[j,k]]
// Deterministic lex-order enumeration: deg1 W[0..31], deg2 W[32..559] (a<=b),
// deg3 W[560..6543] (a<=b<=c). Factorization per row:
//   acc = sum_a W1[a]*x_a
//       + sum_{a<=b} (x_a*x_b) * ( W2[a,b] + sum_{c>=b} W3[a,b,c]*x_c )
//
// V9. Design-space summary (8 rounds of evidence):
//   weights via SMEM (V1 R=1, V7 R=4): spill-free but drain-bound — SMEM
//     returns out-of-order -> lgkmcnt(0) full drains, 15% VALUBusy, 44us.
//   weights via LDS, R=4 (V5/V6/V8): ALWAYS spills — x[128] + in-flight
//     ds_read quads exceed any VGPR cap; sched_barrier(0) didn't bound it
//     (V8: VGPR=256 granted, WRITE 145MB, 144us).
//   weights via LDS, R=2 (V4): spill-free, ~12us — the winning cell.
// V4's overheads: 8 DIFFERENT part codes per block (~100KB unique code/CU
// vs 32KB L1I) and only 2 waves/SIMD.
// V9 = R=2 + LDS weights + 256-thr blocks where ALL 4 waves run the SAME
// part (one ~9KB code path/block), NPART=16, grid = 64 row-tiles x 16 parts
// = 1024 blocks ~ 4 blocks/CU (16 waves/CU TLP). part = bid>>6 so adjacent
// dispatches share part code. VGPR demand ~110-130 -> no spill, headroom
// for scheduler hoisting. Cross-part reduce via atomicAdd (proven 2MB).
// Floor: LDS pipe = 1636 ds_read_b128/CU x ~12cy ~ 8.2us; VALU ~2.9us.

#define NPART 16
#define TOTAL3 5984

__device__ __forceinline__ constexpr int off2(int a, int b) {
    // deg2 base 32; pairs (a<=b) lex order
    return 32 + 32 * a - (a * (a - 1)) / 2 + (b - a);
}

__device__ __forceinline__ constexpr int off3(int a, int b, int c) {
    // deg3 base 560; triples (a<=b<=c) lex order.
    // g3[a] = #triples with first index < a
    constexpr int g3[32] = {
        0,    528,  1024, 1489, 1924, 2330, 2708, 3059,
        3384, 3684, 3960, 4213, 4444, 4654, 4844, 5015,
        5168, 5304, 5424, 5529, 5620, 5698, 5764, 5819,
        5864, 5900, 5928, 5949, 5964, 5974, 5980, 5983};
    return 560 + g3[a] + 32 * (b - a) - ((b * (b - 1)) / 2 - (a * (a - 1)) / 2) + (c - b);
}

// #deg3 triples strictly before pair (a,b)'s c-run in lex order
__device__ __forceinline__ constexpr int cum3(int a, int b) {
    return off3(a, b, b) - 560;
}

// Balanced static ownership of pair (a,b): parts get ~equal deg3-FMA counts.
__device__ __forceinline__ constexpr int owner_of(int a, int b) {
    return (cum3(a, b) * NPART) / TOTAL3;  // monotone, 0..NPART-1
}

template <int PART>
__device__ __forceinline__ void eval_part2(const float* __restrict__ Wl,
                                           const float (&x0)[32],
                                           const float (&x1)[32],
                                           float& r0, float& r1) {
    float a0 = 0.0f, a1 = 0.0f;
#pragma unroll
    for (int a = 0; a < 32; ++a) {
#pragma unroll
        for (int b = a; b < 32; ++b) {
            if (owner_of(a, b) == PART) {  // compile-time filter
                if (a == b) {  // attach deg1 term for feature a here
                    const float w1 = Wl[a];
                    a0 = __builtin_fmaf(w1, x0[a], a0);
                    a1 = __builtin_fmaf(w1, x1[a], a1);
                }
                const float w2 = Wl[off2(a, b)];  // deg2 weight seeds chains
                float s0 = w2, s1 = w2;
#pragma unroll
                for (int c = b; c < 32; ++c) {
                    const float w = Wl[off3(a, b, c)];  // 1 LDS read, 2 FMAs
                    s0 = __builtin_fmaf(w, x0[c], s0);
                    s1 = __builtin_fmaf(w, x1[c], s1);
                }
                a0 = __builtin_fmaf(x0[a] * x0[b], s0, a0);
                a1 = __builtin_fmaf(x1[a] * x1[b], s1, a1);
            }
        }
    }
    r0 = a0;
    r1 = a1;
}

// Block: 256 threads = 4 waves, ALL running the same part (bid >> 6) on
// 512 disjoint rows: thread t owns rows tile*512 + t and tile*512 + 256 + t.
// Cross-part reduce via atomicAdd (out pre-zeroed by hipMemsetAsync).
__global__ __launch_bounds__(256) void PolyLinear_40218073760341_kernel(
    const float* __restrict__ X,   // (rows, 32)
    const float* __restrict__ W,   // (6544,)
    const float* __restrict__ Bp,  // (1,)
    float* __restrict__ out)       // (rows,) — pre-zeroed
{
    const int part = blockIdx.x >> 6;          // 0..15
    const int tile = blockIdx.x & 63;          // 0..63
    const long rbase = (long)tile * 512 + threadIdx.x;

    __shared__ float Wl[6544];  // 26.2 KB staged weights

    // Stage W -> LDS (coalesced float4; 1636 vec4 over 256 threads)
    {
        const float4* Wg = (const float4*)W;
        float4* Wd = (float4*)Wl;
        for (int i = threadIdx.x; i < 1636; i += 256) Wd[i] = Wg[i];
    }

    // Load this thread's 2 rows into registers.
    float x0[32], x1[32];
    {
        const float4* p0 = (const float4*)(X + (rbase) * 32);
        const float4* p1 = (const float4*)(X + (rbase + 256) * 32);
#pragma unroll
        for (int i = 0; i < 8; ++i) {
            const float4 a = p0[i];
            x0[4 * i + 0] = a.x; x0[4 * i + 1] = a.y;
            x0[4 * i + 2] = a.z; x0[4 * i + 3] = a.w;
            const float4 b = p1[i];
            x1[4 * i + 0] = b.x; x1[4 * i + 1] = b.y;
            x1[4 * i + 2] = b.z; x1[4 * i + 3] = b.w;
        }
    }
    __syncthreads();  // Wl ready

    float r0 = 0.0f, r1 = 0.0f;
#define EVAL_CASE(P) \
    case P: eval_part2<P>(Wl, x0, x1, r0, r1); break;
    switch (part) {
        EVAL_CASE(0)  EVAL_CASE(1)  EVAL_CASE(2)  EVAL_CASE(3)
        EVAL_CASE(4)  EVAL_CASE(5)  EVAL_CASE(6)  EVAL_CASE(7)
        EVAL_CASE(8)  EVAL_CASE(9)  EVAL_CASE(10) EVAL_CASE(11)
        EVAL_CASE(12) EVAL_CASE(13) EVAL_CASE(14) EVAL_CASE(15)
    }
#undef EVAL_CASE

    // Bias added exactly once per row (by the part-0 block covering it).
    const float badd = (part == 0) ? Bp[0] : 0.0f;
    atomicAdd(&out[rbase], r0 + badd);
    atomicAdd(&out[rbase + 256], r1 + badd);
}

extern "C" void kernel_launch(void* const* d_in, const int* in_sizes, int n_in,
                              void* d_out, int out_size, void* d_ws, size_t ws_size,
                              hipStream_t stream) {
    const float* X  = (const float*)d_in[0];  // (32768, 32) fp32
    const float* W  = (const float*)d_in[1];  // (1, 6544) fp32
    const float* Bp = (const float*)d_in[2];  // (1,) fp32
    // d_in[3] = idx — deterministic, unused.
    float* out = (float*)d_out;

    const int rows = in_sizes[0] / 32;  // 32768
    hipMemsetAsync(out, 0, (size_t)rows * sizeof(float), stream);
    const int grid = NPART * (rows / 512);  // 16 parts x 64 tiles = 1024
    PolyLinear_40218073760341_kernel<<<grid, 256, 0, stream>>>(X, W, Bp, out);
}